// Round 1
// baseline (305.906 us; speedup 1.0000x reference)
//
#include <hip/hip_runtime.h>
#include <math.h>

// Problem constants
#define NTOT 4096        // H*W = 64*64
#define NBATCH 8
#define CIN 128
#define CK 64
#define CV 64
#define CO 128
#define BN_COUNT 32768.0f // B*H*W

// Workspace layout (float offsets).
#define OFF_YQ    0ul
#define OFF_YK    2097152ul
#define OFF_V     4194304ul
#define OFF_STATS 6291456ul   // [which(2)][sum/sumsq(2)][64]  (atomic-accumulated)
#define OFF_KV    6291712ul   // [8][64][64]                   (atomic-accumulated)
#define OFF_VSUM  6324480ul   // [8][64]                       (atomic-accumulated)
#define OFF_M     6324992ul   // [8][64][128]  (c,o)
#define OFF_D     6390528ul   // [8][128]

// ---------------------------------------------------------------------------
// Kernel 1: LDS-free 1x1-conv GEMM for q, k (Wk,bk) and v (Wv,bv), with BN
// batch-stats (sum/sumsq per channel, q & k) and vsum (v) fused in epilogue.
// grid (32 col-chunks of 128, 8 batch, 3 tensors), block 256 = 4 waves.
// Wave w owns out-channels o = w*16..w*16+15 (wave-uniform -> W reads are
// s_loads), lane owns 2 columns (float2). 32 FMAs per 8B global load; no LDS,
// no barriers. X re-read x4 waves is served by L1/L2.
// ---------------------------------------------------------------------------
__global__ __launch_bounds__(256) void gemm3_fused(
    const float* __restrict__ Xq, const float* __restrict__ Xk, const float* __restrict__ Xv,
    const float* __restrict__ Wk, const float* __restrict__ bk,
    const float* __restrict__ Wv, const float* __restrict__ bv,
    float* __restrict__ Yq, float* __restrict__ Yk, float* __restrict__ Vv,
    float* __restrict__ stats, float* __restrict__ vsum)
{
    const int chunk = blockIdx.x;       // 0..31, 128 cols each
    const int b     = blockIdx.y;
    const int which = blockIdx.z;
    const float* X    = (which == 0) ? Xq : (which == 1) ? Xk : Xv;
    const float* W    = (which == 2) ? Wv : Wk;
    const float* bias = (which == 2) ? bv : bk;
    float* Y          = (which == 0) ? Yq : (which == 1) ? Yk : Vv;

    const int t = threadIdx.x;
    const int lane = t & 63;
    const int wu = __builtin_amdgcn_readfirstlane(t >> 6);   // wave id, uniform

    const int n0 = chunk * 128 + lane * 2;
    const float* Xb = X + (size_t)b * (CIN * NTOT) + n0;
    const float* Wp = W + (size_t)(wu * 16) * CIN;

    float acc0[16], acc1[16];
#pragma unroll
    for (int ki = 0; ki < 16; ++ki) { acc0[ki] = 0.f; acc1[ki] = 0.f; }

#pragma unroll 4
    for (int c = 0; c < CIN; ++c) {
        float2 x = *(const float2*)(Xb + (size_t)c * NTOT);
#pragma unroll
        for (int ki = 0; ki < 16; ++ki) {
            float w = Wp[ki * CIN + c];     // wave-uniform -> s_load
            acc0[ki] += x.x * w;
            acc1[ki] += x.y * w;
        }
    }

    // Epilogue: bias, store, and turn acc into per-thread (sum, sumsq)
    float* Yb = Y + (size_t)b * (CK * NTOT) + n0;
#pragma unroll
    for (int ki = 0; ki < 16; ++ki) {
        const int o = wu * 16 + ki;
        const float bo = bias[o];
        float y0 = acc0[ki] + bo;
        float y1 = acc1[ki] + bo;
        *(float2*)(Yb + (size_t)o * NTOT) = make_float2(y0, y1);
        acc0[ki] = y0 + y1;                 // reuse: partial sum
        acc1[ki] = y0 * y0 + y1 * y1;       // reuse: partial sumsq
    }

    // Wave reduction across 64 lanes (each wave owns unique channels o)
#pragma unroll
    for (int off = 32; off > 0; off >>= 1) {
#pragma unroll
        for (int ki = 0; ki < 16; ++ki) {
            acc0[ki] += __shfl_down(acc0[ki], off, 64);
            acc1[ki] += __shfl_down(acc1[ki], off, 64);
        }
    }
    if (lane == 0) {
        if (which < 2) {
#pragma unroll
            for (int ki = 0; ki < 16; ++ki) {
                const int o = wu * 16 + ki;
                atomicAdd(&stats[which * 128 + o],      acc0[ki]);
                atomicAdd(&stats[which * 128 + 64 + o], acc1[ki]);
            }
        } else {
#pragma unroll
            for (int ki = 0; ki < 16; ++ki)
                atomicAdd(&vsum[b * CV + wu * 16 + ki], acc0[ki]);
        }
    }
}

// ---------------------------------------------------------------------------
// Kernel 2: KV[b,c,v] = sum_n kn[b,c,n]*V[b,v,n].
// kn = L2-normalized-over-c BN(Yk); BN scale/shift computed inline from raw
// stats. grid (32 splits, 8 batch), block 256, 2 chunks of 64 cols each;
// atomicAdd partials into KV.
// ---------------------------------------------------------------------------
__global__ __launch_bounds__(256) void kv_kernel(
    const float* __restrict__ Yk, const float* __restrict__ Vv,
    const float* __restrict__ stats, const float* __restrict__ gamma,
    const float* __restrict__ beta, float* __restrict__ KV)
{
    const int s = blockIdx.x;
    const int b = blockIdx.y;
    __shared__ float sk[64][65];
    __shared__ float sv[64][65];
    __shared__ float rn[64];
    __shared__ float sscl[64], sshf[64];

    const int t = threadIdx.x;
    if (t < 64) {
        float S  = stats[128 + t];          // which = 1 (k)
        float SS = stats[192 + t];
        float mean = S * (1.f / BN_COUNT);
        float var  = SS * (1.f / BN_COUNT) - mean * mean;
        float scl  = gamma[t] * rsqrtf(var + 1e-5f);
        sscl[t] = scl;
        sshf[t] = beta[t] - mean * scl;
    }

    const int tc = t >> 4, tv = t & 15;
    float acc[4][4];
#pragma unroll
    for (int i = 0; i < 4; ++i)
#pragma unroll
        for (int k2 = 0; k2 < 4; ++k2) acc[i][k2] = 0.f;

    const float* Ykb = Yk + (size_t)b * (CK * NTOT);
    const float* Vb  = Vv + (size_t)b * (CK * NTOT);

    for (int ch = 0; ch < 2; ++ch) {
        const int n0 = s * 128 + ch * 64;
        __syncthreads();   // covers sscl init and prior iteration's LDS reads
#pragma unroll
        for (int r = 0; r < 4; ++r) {
            int idx4 = t + r * 256;
            int c  = idx4 >> 4;
            int j4 = (idx4 & 15) << 2;
            float4 kf = *(const float4*)(Ykb + (size_t)c * NTOT + n0 + j4);
            float4 vf = *(const float4*)(Vb  + (size_t)c * NTOT + n0 + j4);
            float scl = sscl[c], sh = sshf[c];
            sk[c][j4 + 0] = kf.x * scl + sh;
            sk[c][j4 + 1] = kf.y * scl + sh;
            sk[c][j4 + 2] = kf.z * scl + sh;
            sk[c][j4 + 3] = kf.w * scl + sh;
            sv[c][j4 + 0] = vf.x; sv[c][j4 + 1] = vf.y;
            sv[c][j4 + 2] = vf.z; sv[c][j4 + 3] = vf.w;
        }
        __syncthreads();
        if (t < 64) {
            float ssum = 0.f;
#pragma unroll 8
            for (int c = 0; c < 64; ++c) { float x = sk[c][t]; ssum += x * x; }
            rn[t] = 1.f / (sqrtf(ssum) + 1e-7f);
        }
        __syncthreads();
#pragma unroll
        for (int r = 0; r < 16; ++r) {
            int idx = t + r * 256;
            sk[idx >> 6][idx & 63] *= rn[idx & 63];
        }
        __syncthreads();
#pragma unroll 4
        for (int j = 0; j < 64; ++j) {
            float a[4], bb[4];
#pragma unroll
            for (int i = 0; i < 4; ++i) a[i]  = sk[tc * 4 + i][j];
#pragma unroll
            for (int i = 0; i < 4; ++i) bb[i] = sv[tv * 4 + i][j];
#pragma unroll
            for (int i = 0; i < 4; ++i)
#pragma unroll
                for (int k2 = 0; k2 < 4; ++k2) acc[i][k2] += a[i] * bb[k2];
        }
    }
    float* KVb = KV + b * (CK * CV);
#pragma unroll
    for (int i = 0; i < 4; ++i)
#pragma unroll
        for (int k2 = 0; k2 < 4; ++k2)
            atomicAdd(&KVb[(tc * 4 + i) * CV + tv * 4 + k2], acc[i][k2]);
}

// ---------------------------------------------------------------------------
// Kernel 3: M[b,c,o] = sum_v KV[b,c,v]*Ww[o,v];  d[b,o] = bw[o] + sum_v Ww[o,v]*vsum[b,v]
// grid 8 (batch), block 256.
// ---------------------------------------------------------------------------
__global__ __launch_bounds__(256) void m_kernel(
    const float* __restrict__ KV, const float* __restrict__ vsum,
    const float* __restrict__ Ww, const float* __restrict__ bw,
    float* __restrict__ M, float* __restrict__ d)
{
    const int b = blockIdx.x;
    __shared__ float sKV[64][65];
    __shared__ float sWw[128][65];
    __shared__ float svs[64];
    const int t = threadIdx.x;

#pragma unroll
    for (int r = 0; r < 16; ++r) {
        int idx = t + r * 256;                       // 0..4095
        sKV[idx >> 6][idx & 63] = KV[b * (CK * CV) + idx];
    }
#pragma unroll
    for (int r = 0; r < 32; ++r) {
        int idx = t + r * 256;                       // 0..8191
        sWw[idx >> 6][idx & 63] = Ww[idx];
    }
    if (t < 64) svs[t] = vsum[b * CV + t];
    __syncthreads();

#pragma unroll
    for (int r = 0; r < 32; ++r) {
        int idx = t + r * 256;
        int c = idx >> 7, o = idx & 127;
        float acc = 0.f;
#pragma unroll 16
        for (int v = 0; v < 64; ++v) acc += sKV[c][v] * sWw[o][v];
        M[(size_t)b * (CK * CO) + idx] = acc;
    }
    if (t < 128) {
        float acc = bw[t];
#pragma unroll 16
        for (int v = 0; v < 64; ++v) acc += sWw[t][v] * svs[v];
        d[b * CO + t] = acc;
    }
}

// ---------------------------------------------------------------------------
// Kernel 4: out[b,o,n] = d[b,o] + sum_c qn[b,c,n] * M[b,c,o]
// qn = L2-normalized-over-c BN(Yq); BN scale/shift computed inline from raw
// stats. grid (64 col-chunks, 8 batch), block 256.
// ---------------------------------------------------------------------------
__global__ __launch_bounds__(256) void out_kernel(
    const float* __restrict__ Yq, const float* __restrict__ stats,
    const float* __restrict__ gamma, const float* __restrict__ beta,
    const float* __restrict__ M, const float* __restrict__ d,
    float* __restrict__ out)
{
    const int chunk = blockIdx.x;
    const int b     = blockIdx.y;
    __shared__ float sM[CK * CO];    // [c][o] flat, 32 KB
    __shared__ float sq[64][68];     // padded, float4-aligned rows
    __shared__ float rn[64];
    __shared__ float sd[CO];
    __shared__ float sscl[64], sshf[64];

    const int t = threadIdx.x;
    const int n0 = chunk * 64;

#pragma unroll
    for (int r = 0; r < 8; ++r) {
        int idx4 = t + r * 256;
        ((float4*)sM)[idx4] = ((const float4*)(M + (size_t)b * (CK * CO)))[idx4];
    }
    if (t < CO) sd[t] = d[b * CO + t];
    if (t < 64) {
        float S  = stats[t];                // which = 0 (q)
        float SS = stats[64 + t];
        float mean = S * (1.f / BN_COUNT);
        float var  = SS * (1.f / BN_COUNT) - mean * mean;
        float scl  = gamma[t] * rsqrtf(var + 1e-5f);
        sscl[t] = scl;
        sshf[t] = beta[t] - mean * scl;
    }
    __syncthreads();   // sscl/sshf ready before sq staging

    const float* Yb = Yq + (size_t)b * (CK * NTOT) + n0;
#pragma unroll
    for (int r = 0; r < 4; ++r) {
        int idx4 = t + r * 256;
        int c  = idx4 >> 4;
        int j4 = (idx4 & 15) << 2;
        float4 xv = *(const float4*)(Yb + (size_t)c * NTOT + j4);
        float scl = sscl[c], sh = sshf[c];
        sq[c][j4 + 0] = xv.x * scl + sh;
        sq[c][j4 + 1] = xv.y * scl + sh;
        sq[c][j4 + 2] = xv.z * scl + sh;
        sq[c][j4 + 3] = xv.w * scl + sh;
    }
    __syncthreads();
    if (t < 64) {
        float ssum = 0.f;
#pragma unroll 8
        for (int c = 0; c < 64; ++c) { float x = sq[c][t]; ssum += x * x; }
        rn[t] = 1.f / (sqrtf(ssum) + 1e-7f);
    }
    __syncthreads();
#pragma unroll
    for (int r = 0; r < 16; ++r) {
        int idx = t + r * 256;
        sq[idx >> 6][idx & 63] *= rn[idx & 63];
    }
    __syncthreads();

    const int j0 = (t & 15) << 2;       // 4 columns
    const int o0 = (t >> 4) << 3;       // 8 out-channels
    float acc[4][8];
#pragma unroll
    for (int jj = 0; jj < 4; ++jj)
#pragma unroll
        for (int oo = 0; oo < 8; ++oo) acc[jj][oo] = sd[o0 + oo];

#pragma unroll 4
    for (int c = 0; c < 64; ++c) {
        float4 qv = *(const float4*)&sq[c][j0];
        float4 m0 = *(const float4*)&sM[c * CO + o0];
        float4 m1 = *(const float4*)&sM[c * CO + o0 + 4];
        float aq[4] = {qv.x, qv.y, qv.z, qv.w};
        float am[8] = {m0.x, m0.y, m0.z, m0.w, m1.x, m1.y, m1.z, m1.w};
#pragma unroll
        for (int jj = 0; jj < 4; ++jj)
#pragma unroll
            for (int oo = 0; oo < 8; ++oo) acc[jj][oo] += aq[jj] * am[oo];
    }

    float* outb = out + (size_t)b * (CO * NTOT) + n0;
#pragma unroll
    for (int oo = 0; oo < 8; ++oo) {
        float4 st = make_float4(acc[0][oo], acc[1][oo], acc[2][oo], acc[3][oo]);
        *(float4*)&outb[(size_t)(o0 + oo) * NTOT + j0] = st;
    }
}

// ---------------------------------------------------------------------------
extern "C" void kernel_launch(void* const* d_in, const int* in_sizes, int n_in,
                              void* d_out, int out_size, void* d_ws, size_t ws_size,
                              hipStream_t stream) {
    (void)in_sizes; (void)n_in; (void)out_size; (void)ws_size;
    const float* q     = (const float*)d_in[0];
    const float* k     = (const float*)d_in[1];
    const float* v     = (const float*)d_in[2];
    const float* Wk    = (const float*)d_in[3];
    const float* bk    = (const float*)d_in[4];
    const float* gamma = (const float*)d_in[5];
    const float* beta  = (const float*)d_in[6];
    const float* Wv    = (const float*)d_in[7];
    const float* bv    = (const float*)d_in[8];
    const float* Ww    = (const float*)d_in[9];
    const float* bw    = (const float*)d_in[10];
    float* out = (float*)d_out;
    float* ws  = (float*)d_ws;

    float* Yq    = ws + OFF_YQ;
    float* Yk    = ws + OFF_YK;
    float* Vv    = ws + OFF_V;
    float* stats = ws + OFF_STATS;
    float* KV    = ws + OFF_KV;
    float* vsum  = ws + OFF_VSUM;
    float* M     = ws + OFF_M;
    float* dd    = ws + OFF_D;

    // zero all atomic-accumulated buffers (stats, KV, vsum are contiguous)
    hipMemsetAsync(stats, 0, (256 + CK * CV * NBATCH + CV * NBATCH) * sizeof(float), stream);

    gemm3_fused<<<dim3(32, NBATCH, 3), 256, 0, stream>>>(
        q, k, v, Wk, bk, Wv, bv, Yq, Yk, Vv, stats, vsum);
    kv_kernel<<<dim3(32, NBATCH), 256, 0, stream>>>(Yk, Vv, stats, gamma, beta, KV);
    m_kernel<<<NBATCH, 256, 0, stream>>>(KV, vsum, Ww, bw, M, dd);
    out_kernel<<<dim3(64, NBATCH), 256, 0, stream>>>(Yq, stats, gamma, beta, M, dd, out);
}